// Round 5
// baseline (2721.271 us; speedup 1.0000x reference)
//
#include <hip/hip_runtime.h>
#include <stdint.h>

// Problem constants (fixed by setup_inputs)
constexpr int Bn = 32, Cc = 24, Hh = 28, Ww = 28;
constexpr int OHt = 24, OWt = 24;           // output spatial
constexpr int CF = 600, HN = 128, TT = 96;  // channels-folded, hidden, spikes
constexpr int NPIX = OHt * OWt;             // 576
constexpr int NSAMP = Bn * TT * NPIX;       // 1,769,472
constexpr int NLOG = Bn * Cc * Hh * Ww;     // 602,112
constexpr int NBIN = 640;                   // thr table bins, bgap in [-8, 12)

// Approx-argmax confidence margin: must exceed 2x the absolute error of
// vh = lp - ln2*log2(-log2(u)) vs exact v - C. With v_log_f32 at ~1 ulp
// relative, total abs error <= ~1e-5; 2^-12 gives 12x headroom.
constexpr float MARGIN = 2.44140625e-4f;    // 2^-12
constexpr float LN2 = 0.6931471805599453f;
constexpr float CGUM = 0.36651292058166433f;  // -ln(ln 2): vh = v - CGUM

// ---- JAX threefry2x32, key(42) -> (0, 42), partitionable counter mode ----
// Caller pre-adds the ks1=42 key injection: pass x1 = counter + 42.
__device__ __forceinline__ uint32_t threefry_0_42_pre(uint32_t x1) {
  const uint32_t ks1 = 42u, ks2 = 0x1BD11BF0u;  // 0x1BD11BDA ^ 0 ^ 42
  uint32_t x0 = x1;                                      // 0 + x1
  x1 = __builtin_rotateleft32(x1, 13) ^ x0;
  x0 += x1; x1 = __builtin_rotateleft32(x1, 15) ^ x0;
  x0 += x1; x1 = __builtin_rotateleft32(x1, 26) ^ x0;
  x0 += x1; x1 = __builtin_rotateleft32(x1,  6) ^ x0;
  x0 += ks1; x1 += ks2 + 1u;
  x0 += x1; x1 = __builtin_rotateleft32(x1, 17) ^ x0;
  x0 += x1; x1 = __builtin_rotateleft32(x1, 29) ^ x0;
  x0 += x1; x1 = __builtin_rotateleft32(x1, 16) ^ x0;
  x0 += x1; x1 = __builtin_rotateleft32(x1, 24) ^ x0;
  x0 += ks2; x1 += 2u;
  x0 += x1; x1 = __builtin_rotateleft32(x1, 13) ^ x0;
  x0 += x1; x1 = __builtin_rotateleft32(x1, 15) ^ x0;
  x0 += x1; x1 = __builtin_rotateleft32(x1, 26) ^ x0;
  x0 += x1; x1 = __builtin_rotateleft32(x1,  6) ^ x0;
  x1 += ks1 + 3u;
  x0 += x1; x1 = __builtin_rotateleft32(x1, 17) ^ x0;
  x0 += x1; x1 = __builtin_rotateleft32(x1, 29) ^ x0;
  x0 += x1; x1 = __builtin_rotateleft32(x1, 16) ^ x0;
  x0 += x1; x1 = __builtin_rotateleft32(x1, 24) ^ x0;
  x0 += ks1; x1 += ks2 + 4u;
  x0 += x1; x1 = __builtin_rotateleft32(x1, 13) ^ x0;
  x0 += x1; x1 = __builtin_rotateleft32(x1, 15) ^ x0;
  x0 += x1; x1 = __builtin_rotateleft32(x1, 26) ^ x0;
  x0 += x1; x1 = __builtin_rotateleft32(x1,  6) ^ x0;
  x0 += ks2; x1 += 5u;
  return x0 ^ x1;
}

__global__ __launch_bounds__(256) void k_log(const float* __restrict__ in,
                                             float* __restrict__ lp) {
  int i = blockIdx.x * 256 + threadIdx.x;
  if (i < NLOG) lp[i] = logf(in[i]);
}

// Per-(b,pixel) max of the 600 candidate log-probs (for the bits-gate bound).
__global__ __launch_bounds__(256) void k_lpmax(const float* __restrict__ lp,
                                               float* __restrict__ out) {
  int pid = blockIdx.x * 256 + threadIdx.x;  // (b, x, y)
  if (pid >= Bn * NPIX) return;
  int y = pid % OWt;
  int x = (pid / OWt) % OHt;
  int b = pid / NPIX;
  const float* p = lp + (b * Cc) * (Hh * Ww) + x * Ww + y;
  float m = -3.0e38f;
  for (int c = 0; c < Cc; ++c) {
    const float* pc = p + c * (Hh * Ww);
    #pragma unroll
    for (int ki = 0; ki < 5; ++ki)
      #pragma unroll
      for (int kj = 0; kj < 5; ++kj) m = fmaxf(m, pc[ki * Ww + kj]);
  }
  out[pid] = m;
}

// Conservative bits-threshold: admit every u whose exact (ocml) value could
// come within the table slack of a comparator with gap bgap = b - lpmax.
//   G3 = bgap - 2^-8; U_lo <= inverse via +/-2^-16 expf slop; key -64.
// Monotone non-decreasing in bgap; stale/looser thr is always sound.
__device__ __forceinline__ uint32_t mkthr(float bgap) {
  float g3 = bgap - 0.00390625f;
  float e1 = __expf(-g3) * 1.0000153f;   // >= exp(-g3)
  float ul = __expf(-e1) * 0.9999847f;   // <= exp(-e1) <= inverse
  int kt = (int)(ul * 8388608.0f) - 64;
  return (kt < 1) ? 0u : ((uint32_t)kt << 9);
}

// Exact value (bit-identical to the reference / all prior passing kernels).
__device__ __forceinline__ float exact_v(uint32_t bits, float lp) {
  uint32_t key = bits >> 9;
  float f = __uint_as_float(key | 0x3f800000u) - 1.0f;
  float u = (f == 0.0f) ? 1.17549435e-38f : f;  // max(tiny, f)
  float l1 = logf(u);
  return -logf(-l1) + lp;
}

// Cold path: full bit-exact first-max-wins rescan of one sample.
__device__ __attribute__((noinline)) int exact_argmax(
    uint32_t base, const float* __restrict__ lpb) {
  float best = -1e30f;
  int bi = 0;
  int cf = 0;
  #pragma unroll 1
  for (int c = 0; c < Cc; ++c) {
    const float* lpc = lpb + c * (Hh * Ww);
    #pragma unroll 1
    for (int ki = 0; ki < 5; ++ki)
      #pragma unroll
      for (int kj = 0; kj < 5; ++kj) {
        float v = exact_v(threefry_0_42_pre(base + (uint32_t)cf),
                          lpc[ki * Ww + kj]);
        if (v > best) { best = v; bi = cf; }  // strict >: first-max-wins
        ++cf;
      }
  }
  return bi;
}

// One thread per t-QUAD: samples (b, t+24k, x, y), k=0..3, share the lp
// stream, lpmax, and loop overhead; 4 independent threefry chains = 4x ILP.
// Phase A: register bits-gate (1 cmp), masked ~16-inst approx top-2 tracker
// (2x v_log2), LDS only for the thr table inside the masked block.
// Phase B: confident approx argmax, or rare exact rescan when top-2 gap
// < MARGIN (covers approx error + exact ties; see margin derivation above).
__global__ __launch_bounds__(256) void k_sample(const float* __restrict__ logp,
                                                const float* __restrict__ lpmaxa,
                                                int* __restrict__ spikes) {
  __shared__ uint32_t thr_tab[NBIN];
  for (int i = threadIdx.x; i < NBIN; i += 256)
    thr_tab[i] = mkthr(__builtin_fmaf((float)i, 0.03125f, -8.0f));
  __syncthreads();

  int tid = blockIdx.x * 256 + threadIdx.x;  // [0, NSAMP/4)
  int y = tid % OWt;
  int x = (tid / OWt) % OHt;
  int t = (tid / NPIX) % 24;
  int b = tid / (NPIX * 24);
  int sid0 = ((b * TT + t) * OHt + x) * OWt + y;
  // sample k = sid0 + k*24*NPIX; counter stride = 24*NPIX*600 = 8,294,400
  uint32_t ctr0 = (uint32_t)sid0 * 600u + 42u;  // ks1 pre-added
  const float* lpb = logp + (b * Cc) * (Hh * Ww) + x * Ww + y;
  float lpmax = lpmaxa[(b * OHt + x) * OWt + y];
  // bin index K: bidx = fma(bestA, 32, K) = 32*(v - lpmax + 8) + 255 biased
  float K = __builtin_fmaf(-32.0f, lpmax, 255.0f + 32.0f * CGUM);

  float bA0 = -1e30f, bA1 = -1e30f, bA2 = -1e30f, bA3 = -1e30f;
  float sA0 = -2e30f, sA1 = -2e30f, sA2 = -2e30f, sA3 = -2e30f;
  int bi0 = 0, bi1 = 0, bi2 = 0, bi3 = 0;
  uint32_t th0 = 0u, th1 = 0u, th2 = 0u, th3 = 0u;  // 0 => admit-all

#define AUPD(kk, BITS, BA, SA, BI, TH)                                      \
  if ((BITS) >= (TH)) {                                                     \
    uint32_t key = (BITS) >> 9;                                             \
    float f = __uint_as_float(key | 0x3f800000u) - 1.0f;                    \
    float u = (f == 0.0f) ? 1.17549435e-38f : f;                            \
    float lg = __log2f(u);                       /* < 0 always */           \
    float n = __log2f(-lg);                                                 \
    float vh = __builtin_fmaf(-LN2, n, lp);      /* ~ v - CGUM */           \
    float nb = fmaxf(BA, vh);                                               \
    SA = fmaxf(SA, fminf(BA, vh));                                          \
    if (vh > BA) BI = cf;                                                   \
    BA = nb;                                                                \
    float bx = __builtin_fmaf(nb, 32.0f, K);                                \
    bx = fminf(fmaxf(bx, 0.0f), 639.0f);                                    \
    TH = thr_tab[(int)bx];                                                  \
  }

  int cf = 0;
  #pragma unroll 1
  for (int c = 0; c < Cc; ++c) {
    const float* lpc = lpb + c * (Hh * Ww);
    #pragma unroll 1
    for (int ki = 0; ki < 5; ++ki) {
      #pragma unroll
      for (int kj = 0; kj < 5; ++kj) {
        float lp = lpc[ki * Ww + kj];
        uint32_t c0 = ctr0 + (uint32_t)cf;
        uint32_t bb0 = threefry_0_42_pre(c0);
        uint32_t bb1 = threefry_0_42_pre(c0 + 8294400u);
        uint32_t bb2 = threefry_0_42_pre(c0 + 16588800u);
        uint32_t bb3 = threefry_0_42_pre(c0 + 24883200u);
        AUPD(0, bb0, bA0, sA0, bi0, th0)
        AUPD(1, bb1, bA1, sA1, bi1, th1)
        AUPD(2, bb2, bA2, sA2, bi2, th2)
        AUPD(3, bb3, bA3, sA3, bi3, th3)
        ++cf;
      }
    }
  }
#undef AUPD

  // Phase B: resolve. Confident if top-2 approx gap >= MARGIN.
  int* sp0 = spikes + sid0;
  sp0[0] = (bA0 - sA0 >= MARGIN) ? bi0 : exact_argmax(ctr0, lpb);
  sp0[24 * NPIX] =
      (bA1 - sA1 >= MARGIN) ? bi1 : exact_argmax(ctr0 + 8294400u, lpb);
  sp0[48 * NPIX] =
      (bA2 - sA2 >= MARGIN) ? bi2 : exact_argmax(ctr0 + 16588800u, lpb);
  sp0[72 * NPIX] =
      (bA3 - sA3 >= MARGIN) ? bi3 : exact_argmax(ctr0 + 24883200u, lpb);
}

// One wave per pixel, 2 neurons per lane; 96 sequential normalized updates.
__global__ __launch_bounds__(256) void k_recur(
    const int* __restrict__ spikes, const float* __restrict__ weights,
    const float* __restrict__ eps_xy, const float* __restrict__ eps_t,
    const float* __restrict__ eps0p, const float* __restrict__ h_init,
    float* __restrict__ out) {
  int wid = blockIdx.x * 4 + (threadIdx.x >> 6);  // pixel id in [0, 18432)
  int lane = threadIdx.x & 63;
  int y = wid % OWt;
  int x = (wid / OWt) % OHt;
  int b = wid / NPIX;
  float g0 = h_init[lane];
  float g1 = h_init[lane + 64];
  float e0 = eps0p[0];
  const int* sp = spikes + (b * TT) * NPIX + x * OWt + y;
  const float* ex = eps_xy + (x * OWt + y) * 25;
  for (int t = 0; t < TT; ++t) {
    int s = sp[t * NPIX];  // wave-uniform
    const float* wr = weights + s * HN;
    float wg0 = wr[lane] * g0;
    float wg1 = wr[lane + 64] * g1;
    float sum = wg0 + wg1;
    #pragma unroll
    for (int off = 32; off > 0; off >>= 1) sum += __shfl_xor(sum, off, 64);
    float es = ex[s % 25] * (eps_t[t] * e0);  // eps * (et * eps0)
    float factor = es / sum;
    if (!__builtin_isfinite(factor)) factor = 0.0f;  // nan_to_num
    float d = 1.0f + es;
    g0 = (g0 + wg0 * factor) / d;
    g1 = (g1 + wg1 * factor) / d;
  }
  out[((b * HN + lane) * OHt + x) * OWt + y] = g0;
  out[((b * HN + lane + 64) * OHt + x) * OWt + y] = g1;
}

extern "C" void kernel_launch(void* const* d_in, const int* in_sizes, int n_in,
                              void* d_out, int out_size, void* d_ws, size_t ws_size,
                              hipStream_t stream) {
  const float* input   = (const float*)d_in[0];
  const float* eps_xy  = (const float*)d_in[1];
  const float* eps0    = (const float*)d_in[2];
  const float* eps_t   = (const float*)d_in[3];
  const float* weights = (const float*)d_in[4];
  const float* h_init  = (const float*)d_in[5];
  // d_in[6] = number_of_spikes (=96, hardcoded)

  float* logp = (float*)d_ws;                                // 602,112 f32
  int* spikes = (int*)((char*)d_ws + NLOG * sizeof(float));  // 1,769,472 i32
  // lpmax (18432 f32) staged in d_out; k_recur fully overwrites it later.
  float* lpmax = (float*)d_out;

  k_log<<<(NLOG + 255) / 256, 256, 0, stream>>>(input, logp);
  k_lpmax<<<(Bn * NPIX + 255) / 256, 256, 0, stream>>>(logp, lpmax);
  k_sample<<<(NSAMP / 4) / 256, 256, 0, stream>>>(logp, lpmax, spikes);
  k_recur<<<(Bn * NPIX) / 4, 256, 0, stream>>>(spikes, weights, eps_xy, eps_t,
                                               eps0, h_init, (float*)d_out);
}

// Round 6
// 2665.114 us; speedup vs baseline: 1.0211x; 1.0211x over previous
//
#include <hip/hip_runtime.h>
#include <stdint.h>

// Problem constants (fixed by setup_inputs)
constexpr int Bn = 32, Cc = 24, Hh = 28, Ww = 28;
constexpr int OHt = 24, OWt = 24;           // output spatial
constexpr int CF = 600, HN = 128, TT = 96;  // channels-folded, hidden, spikes
constexpr int NPIX = OHt * OWt;             // 576
constexpr int NSAMP = Bn * TT * NPIX;       // 1,769,472
constexpr int NLOG = Bn * Cc * Hh * Ww;     // 602,112
constexpr int NBIN = 640;                   // thr table bins, bgap in [-8, 12)

// Approx-argmax confidence margin: must exceed 2x the absolute error of
// vh = lp - ln2*log2(-log2(u)) vs exact v - C. With v_log_f32 at ~1 ulp
// relative, total abs error <= ~1e-5; 2^-12 gives 12x headroom.
constexpr float MARGIN = 2.44140625e-4f;    // 2^-12
constexpr float LN2 = 0.6931471805599453f;
constexpr float CGUM = 0.36651292058166433f;  // -ln(ln 2): vh = v - CGUM

// ---- JAX threefry2x32, key(42) -> (0, 42), partitionable counter mode ----
// Caller pre-adds the ks1=42 key injection: pass x1 = counter + 42.
__device__ __forceinline__ uint32_t threefry_0_42_pre(uint32_t x1) {
  const uint32_t ks1 = 42u, ks2 = 0x1BD11BF0u;  // 0x1BD11BDA ^ 0 ^ 42
  uint32_t x0 = x1;                                      // 0 + x1
  x1 = __builtin_rotateleft32(x1, 13) ^ x0;
  x0 += x1; x1 = __builtin_rotateleft32(x1, 15) ^ x0;
  x0 += x1; x1 = __builtin_rotateleft32(x1, 26) ^ x0;
  x0 += x1; x1 = __builtin_rotateleft32(x1,  6) ^ x0;
  x0 += ks1; x1 += ks2 + 1u;
  x0 += x1; x1 = __builtin_rotateleft32(x1, 17) ^ x0;
  x0 += x1; x1 = __builtin_rotateleft32(x1, 29) ^ x0;
  x0 += x1; x1 = __builtin_rotateleft32(x1, 16) ^ x0;
  x0 += x1; x1 = __builtin_rotateleft32(x1, 24) ^ x0;
  x0 += ks2; x1 += 2u;
  x0 += x1; x1 = __builtin_rotateleft32(x1, 13) ^ x0;
  x0 += x1; x1 = __builtin_rotateleft32(x1, 15) ^ x0;
  x0 += x1; x1 = __builtin_rotateleft32(x1, 26) ^ x0;
  x0 += x1; x1 = __builtin_rotateleft32(x1,  6) ^ x0;
  x1 += ks1 + 3u;
  x0 += x1; x1 = __builtin_rotateleft32(x1, 17) ^ x0;
  x0 += x1; x1 = __builtin_rotateleft32(x1, 29) ^ x0;
  x0 += x1; x1 = __builtin_rotateleft32(x1, 16) ^ x0;
  x0 += x1; x1 = __builtin_rotateleft32(x1, 24) ^ x0;
  x0 += ks1; x1 += ks2 + 4u;
  x0 += x1; x1 = __builtin_rotateleft32(x1, 13) ^ x0;
  x0 += x1; x1 = __builtin_rotateleft32(x1, 15) ^ x0;
  x0 += x1; x1 = __builtin_rotateleft32(x1, 26) ^ x0;
  x0 += x1; x1 = __builtin_rotateleft32(x1,  6) ^ x0;
  x0 += ks2; x1 += 5u;
  return x0 ^ x1;
}

__global__ __launch_bounds__(256) void k_log(const float* __restrict__ in,
                                             float* __restrict__ lp) {
  int i = blockIdx.x * 256 + threadIdx.x;
  if (i < NLOG) lp[i] = logf(in[i]);
}

// Per-(b,pixel) max of the 600 candidate log-probs (for the bits-gate bound).
__global__ __launch_bounds__(256) void k_lpmax(const float* __restrict__ lp,
                                               float* __restrict__ out) {
  int pid = blockIdx.x * 256 + threadIdx.x;  // (b, x, y)
  if (pid >= Bn * NPIX) return;
  int y = pid % OWt;
  int x = (pid / OWt) % OHt;
  int b = pid / NPIX;
  const float* p = lp + (b * Cc) * (Hh * Ww) + x * Ww + y;
  float m = -3.0e38f;
  for (int c = 0; c < Cc; ++c) {
    const float* pc = p + c * (Hh * Ww);
    #pragma unroll
    for (int ki = 0; ki < 5; ++ki)
      #pragma unroll
      for (int kj = 0; kj < 5; ++kj) m = fmaxf(m, pc[ki * Ww + kj]);
  }
  out[pid] = m;
}

// Conservative bits-threshold: admit every u whose exact (ocml) value could
// come within the table slack of a comparator with gap bgap = b - lpmax.
//   G3 = bgap - 2^-8; U_lo <= inverse via +/-2^-16 expf slop; key -64.
// Monotone non-decreasing in bgap; stale/looser thr is always sound.
__device__ __forceinline__ uint32_t mkthr(float bgap) {
  float g3 = bgap - 0.00390625f;
  float e1 = __expf(-g3) * 1.0000153f;   // >= exp(-g3)
  float ul = __expf(-e1) * 0.9999847f;   // <= exp(-e1) <= inverse
  int kt = (int)(ul * 8388608.0f) - 64;
  return (kt < 1) ? 0u : ((uint32_t)kt << 9);
}

// Exact value (bit-identical to the reference / all prior passing kernels).
__device__ __forceinline__ float exact_v(uint32_t bits, float lp) {
  uint32_t key = bits >> 9;
  float f = __uint_as_float(key | 0x3f800000u) - 1.0f;
  float u = (f == 0.0f) ? 1.17549435e-38f : f;  // max(tiny, f)
  float l1 = logf(u);
  return -logf(-l1) + lp;
}

// Cold path: full bit-exact first-max-wins rescan of one sample.
__device__ __attribute__((noinline)) int exact_argmax(
    uint32_t base, const float* __restrict__ lpb) {
  float best = -1e30f;
  int bi = 0;
  int cf = 0;
  #pragma unroll 1
  for (int c = 0; c < Cc; ++c) {
    const float* lpc = lpb + c * (Hh * Ww);
    #pragma unroll 1
    for (int ki = 0; ki < 5; ++ki)
      #pragma unroll
      for (int kj = 0; kj < 5; ++kj) {
        float v = exact_v(threefry_0_42_pre(base + (uint32_t)cf),
                          lpc[ki * Ww + kj]);
        if (v > best) { best = v; bi = cf; }  // strict >: first-max-wins
        ++cf;
      }
  }
  return bi;
}

// One thread per t-PAIR: samples (b,t,x,y) and (b,t+48,x,y) share the lp
// stream, lpmax, and loop overhead; 2 independent threefry chains = 2x ILP.
// (Round-5 lesson: 4-sample grouping shrank the grid to 1728 blocks ->
// occupancy 41%, latency stalls; NSAMP/2 = 3456 blocks sits at ~69%.)
// Phase A: register bits-gate (1 cmp), masked ~18-inst approx top-2 tracker
// (2x v_log2), LDS only for the thr table inside the masked block.
// Phase B: confident approx argmax, or rare exact rescan when top-2 gap
// < MARGIN (covers approx error + exact ties; see margin derivation above).
__global__ __launch_bounds__(256) void k_sample(const float* __restrict__ logp,
                                                const float* __restrict__ lpmaxa,
                                                int* __restrict__ spikes) {
  __shared__ uint32_t thr_tab[NBIN];
  for (int i = threadIdx.x; i < NBIN; i += 256)
    thr_tab[i] = mkthr(__builtin_fmaf((float)i, 0.03125f, -8.0f));
  __syncthreads();

  int tid = blockIdx.x * 256 + threadIdx.x;  // [0, NSAMP/2)
  int y = tid % OWt;
  int x = (tid / OWt) % OHt;
  int t = (tid / NPIX) % 48;
  int b = tid / (NPIX * 48);
  int sid1 = ((b * TT + t) * OHt + x) * OWt + y;
  // sample 2 = sid1 + 48*NPIX; counter stride = 48*NPIX*600 = 16,588,800
  uint32_t ctr1 = (uint32_t)sid1 * 600u + 42u;  // ks1 pre-added
  const float* lpb = logp + (b * Cc) * (Hh * Ww) + x * Ww + y;
  float lpmax = lpmaxa[(b * OHt + x) * OWt + y];
  // bin index: bidx = fma(bestA, 32, K) = 32*(v - lpmax + 8) + 255 biased
  float K = __builtin_fmaf(-32.0f, lpmax, 255.0f + 32.0f * CGUM);

  float bA1 = -1e30f, bA2 = -1e30f;   // approx running max (vh-space)
  float sA1 = -2e30f, sA2 = -2e30f;   // approx running second-max
  int bi1 = 0, bi2 = 0;
  uint32_t th1 = 0u, th2 = 0u;        // 0 => admit-all (warm-up)

#define AUPD(BITS, BA, SA, BI, TH)                                          \
  if ((BITS) >= (TH)) {                                                     \
    uint32_t key = (BITS) >> 9;                                             \
    float f = __uint_as_float(key | 0x3f800000u) - 1.0f;                    \
    float u = (f == 0.0f) ? 1.17549435e-38f : f;                            \
    float lg = __log2f(u);                       /* < 0 always */           \
    float n = __log2f(-lg);                                                 \
    float vh = __builtin_fmaf(-LN2, n, lp);      /* ~ v - CGUM */           \
    float nb = fmaxf(BA, vh);                                               \
    SA = fmaxf(SA, fminf(BA, vh));                                          \
    if (vh > BA) BI = cf;                                                   \
    BA = nb;                                                                \
    float bx = __builtin_fmaf(nb, 32.0f, K);                                \
    bx = fminf(fmaxf(bx, 0.0f), 639.0f);                                    \
    TH = thr_tab[(int)bx];                                                  \
  }

  int cf = 0;
  #pragma unroll 1
  for (int c = 0; c < Cc; ++c) {
    const float* lpc = lpb + c * (Hh * Ww);
    #pragma unroll 1
    for (int ki = 0; ki < 5; ++ki) {
      #pragma unroll
      for (int kj = 0; kj < 5; ++kj) {
        float lp = lpc[ki * Ww + kj];
        uint32_t c1 = ctr1 + (uint32_t)cf;
        uint32_t bb1 = threefry_0_42_pre(c1);
        uint32_t bb2 = threefry_0_42_pre(c1 + 16588800u);
        AUPD(bb1, bA1, sA1, bi1, th1)
        AUPD(bb2, bA2, sA2, bi2, th2)
        ++cf;
      }
    }
  }
#undef AUPD

  // Phase B: resolve. Confident if top-2 approx gap >= MARGIN.
  spikes[sid1] = (bA1 - sA1 >= MARGIN) ? bi1 : exact_argmax(ctr1, lpb);
  spikes[sid1 + 48 * NPIX] =
      (bA2 - sA2 >= MARGIN) ? bi2 : exact_argmax(ctr1 + 16588800u, lpb);
}

// One wave per pixel, 2 neurons per lane; 96 sequential normalized updates.
__global__ __launch_bounds__(256) void k_recur(
    const int* __restrict__ spikes, const float* __restrict__ weights,
    const float* __restrict__ eps_xy, const float* __restrict__ eps_t,
    const float* __restrict__ eps0p, const float* __restrict__ h_init,
    float* __restrict__ out) {
  int wid = blockIdx.x * 4 + (threadIdx.x >> 6);  // pixel id in [0, 18432)
  int lane = threadIdx.x & 63;
  int y = wid % OWt;
  int x = (wid / OWt) % OHt;
  int b = wid / NPIX;
  float g0 = h_init[lane];
  float g1 = h_init[lane + 64];
  float e0 = eps0p[0];
  const int* sp = spikes + (b * TT) * NPIX + x * OWt + y;
  const float* ex = eps_xy + (x * OWt + y) * 25;
  for (int t = 0; t < TT; ++t) {
    int s = sp[t * NPIX];  // wave-uniform
    const float* wr = weights + s * HN;
    float wg0 = wr[lane] * g0;
    float wg1 = wr[lane + 64] * g1;
    float sum = wg0 + wg1;
    #pragma unroll
    for (int off = 32; off > 0; off >>= 1) sum += __shfl_xor(sum, off, 64);
    float es = ex[s % 25] * (eps_t[t] * e0);  // eps * (et * eps0)
    float factor = es / sum;
    if (!__builtin_isfinite(factor)) factor = 0.0f;  // nan_to_num
    float d = 1.0f + es;
    g0 = (g0 + wg0 * factor) / d;
    g1 = (g1 + wg1 * factor) / d;
  }
  out[((b * HN + lane) * OHt + x) * OWt + y] = g0;
  out[((b * HN + lane + 64) * OHt + x) * OWt + y] = g1;
}

extern "C" void kernel_launch(void* const* d_in, const int* in_sizes, int n_in,
                              void* d_out, int out_size, void* d_ws, size_t ws_size,
                              hipStream_t stream) {
  const float* input   = (const float*)d_in[0];
  const float* eps_xy  = (const float*)d_in[1];
  const float* eps0    = (const float*)d_in[2];
  const float* eps_t   = (const float*)d_in[3];
  const float* weights = (const float*)d_in[4];
  const float* h_init  = (const float*)d_in[5];
  // d_in[6] = number_of_spikes (=96, hardcoded)

  float* logp = (float*)d_ws;                                // 602,112 f32
  int* spikes = (int*)((char*)d_ws + NLOG * sizeof(float));  // 1,769,472 i32
  // lpmax (18432 f32) staged in d_out; k_recur fully overwrites it later.
  float* lpmax = (float*)d_out;

  k_log<<<(NLOG + 255) / 256, 256, 0, stream>>>(input, logp);
  k_lpmax<<<(Bn * NPIX + 255) / 256, 256, 0, stream>>>(logp, lpmax);
  k_sample<<<(NSAMP / 2) / 256, 256, 0, stream>>>(logp, lpmax, spikes);
  k_recur<<<(Bn * NPIX) / 4, 256, 0, stream>>>(spikes, weights, eps_xy, eps_t,
                                               eps0, h_init, (float*)d_out);
}

// Round 7
// 2578.873 us; speedup vs baseline: 1.0552x; 1.0334x over previous
//
#include <hip/hip_runtime.h>
#include <stdint.h>

// Problem constants (fixed by setup_inputs)
constexpr int Bn = 32, Cc = 24, Hh = 28, Ww = 28;
constexpr int OHt = 24, OWt = 24;           // output spatial
constexpr int CF = 600, HN = 128, TT = 96;  // channels-folded, hidden, spikes
constexpr int NPIX = OHt * OWt;             // 576
constexpr int NSAMP = Bn * TT * NPIX;       // 1,769,472
constexpr int NLOG = Bn * Cc * Hh * Ww;     // 602,112
constexpr int NBIN = 640;                   // thr table bins, bgap in [-8, 12)

// Approx-argmax confidence margin: must exceed 2x the absolute error of
// vh = lp - ln2*log2(-log2(u)) vs exact v - C. With v_log_f32 at ~1 ulp
// relative, total abs error <= ~1e-5; 2^-12 gives 12x headroom.
constexpr float MARGIN = 2.44140625e-4f;    // 2^-12
constexpr float LN2 = 0.6931471805599453f;
constexpr float CGUM = 0.36651292058166433f;  // -ln(ln 2): vh = v - CGUM

// ---- JAX threefry2x32, key(42) -> (0, 42), partitionable counter mode ----
// Caller pre-adds the ks1=42 key injection: pass x1 = counter + 42.
__device__ __forceinline__ uint32_t threefry_0_42_pre(uint32_t x1) {
  const uint32_t ks1 = 42u, ks2 = 0x1BD11BF0u;  // 0x1BD11BDA ^ 0 ^ 42
  uint32_t x0 = x1;                                      // 0 + x1
  x1 = __builtin_rotateleft32(x1, 13) ^ x0;
  x0 += x1; x1 = __builtin_rotateleft32(x1, 15) ^ x0;
  x0 += x1; x1 = __builtin_rotateleft32(x1, 26) ^ x0;
  x0 += x1; x1 = __builtin_rotateleft32(x1,  6) ^ x0;
  x0 += ks1; x1 += ks2 + 1u;
  x0 += x1; x1 = __builtin_rotateleft32(x1, 17) ^ x0;
  x0 += x1; x1 = __builtin_rotateleft32(x1, 29) ^ x0;
  x0 += x1; x1 = __builtin_rotateleft32(x1, 16) ^ x0;
  x0 += x1; x1 = __builtin_rotateleft32(x1, 24) ^ x0;
  x0 += ks2; x1 += 2u;
  x0 += x1; x1 = __builtin_rotateleft32(x1, 13) ^ x0;
  x0 += x1; x1 = __builtin_rotateleft32(x1, 15) ^ x0;
  x0 += x1; x1 = __builtin_rotateleft32(x1, 26) ^ x0;
  x0 += x1; x1 = __builtin_rotateleft32(x1,  6) ^ x0;
  x1 += ks1 + 3u;
  x0 += x1; x1 = __builtin_rotateleft32(x1, 17) ^ x0;
  x0 += x1; x1 = __builtin_rotateleft32(x1, 29) ^ x0;
  x0 += x1; x1 = __builtin_rotateleft32(x1, 16) ^ x0;
  x0 += x1; x1 = __builtin_rotateleft32(x1, 24) ^ x0;
  x0 += ks1; x1 += ks2 + 4u;
  x0 += x1; x1 = __builtin_rotateleft32(x1, 13) ^ x0;
  x0 += x1; x1 = __builtin_rotateleft32(x1, 15) ^ x0;
  x0 += x1; x1 = __builtin_rotateleft32(x1, 26) ^ x0;
  x0 += x1; x1 = __builtin_rotateleft32(x1,  6) ^ x0;
  x0 += ks2; x1 += 5u;
  return x0 ^ x1;
}

__global__ __launch_bounds__(256) void k_log(const float* __restrict__ in,
                                             float* __restrict__ lp) {
  int i = blockIdx.x * 256 + threadIdx.x;
  if (i < NLOG) lp[i] = logf(in[i]);
}

// Per-(b,pixel) max of the 600 candidate log-probs (for the bits-gate bound).
__global__ __launch_bounds__(256) void k_lpmax(const float* __restrict__ lp,
                                               float* __restrict__ out) {
  int pid = blockIdx.x * 256 + threadIdx.x;  // (b, x, y)
  if (pid >= Bn * NPIX) return;
  int y = pid % OWt;
  int x = (pid / OWt) % OHt;
  int b = pid / NPIX;
  const float* p = lp + (b * Cc) * (Hh * Ww) + x * Ww + y;
  float m = -3.0e38f;
  for (int c = 0; c < Cc; ++c) {
    const float* pc = p + c * (Hh * Ww);
    #pragma unroll
    for (int ki = 0; ki < 5; ++ki)
      #pragma unroll
      for (int kj = 0; kj < 5; ++kj) m = fmaxf(m, pc[ki * Ww + kj]);
  }
  out[pid] = m;
}

// Conservative bits-threshold: admit every u whose exact (ocml) value could
// come within the table slack of a comparator with gap bgap = b - lpmax.
//   G3 = bgap - 2^-8; U_lo <= inverse via +/-2^-16 expf slop; key -64.
// Monotone non-decreasing in bgap; stale/looser thr is always sound.
__device__ __forceinline__ uint32_t mkthr(float bgap) {
  float g3 = bgap - 0.00390625f;
  float e1 = __expf(-g3) * 1.0000153f;   // >= exp(-g3)
  float ul = __expf(-e1) * 0.9999847f;   // <= exp(-e1) <= inverse
  int kt = (int)(ul * 8388608.0f) - 64;
  return (kt < 1) ? 0u : ((uint32_t)kt << 9);
}

// Exact value (bit-identical to the reference / all prior passing kernels).
__device__ __forceinline__ float exact_v(uint32_t bits, float lp) {
  uint32_t key = bits >> 9;
  float f = __uint_as_float(key | 0x3f800000u) - 1.0f;
  float u = (f == 0.0f) ? 1.17549435e-38f : f;  // max(tiny, f)
  float l1 = logf(u);
  return -logf(-l1) + lp;
}

// Cold path: full bit-exact first-max-wins rescan of one sample.
__device__ __attribute__((noinline)) int exact_argmax(
    uint32_t base, const float* __restrict__ lpb) {
  float best = -1e30f;
  int bi = 0;
  int cf = 0;
  #pragma unroll 1
  for (int c = 0; c < Cc; ++c) {
    const float* lpc = lpb + c * (Hh * Ww);
    #pragma unroll 1
    for (int ki = 0; ki < 5; ++ki)
      #pragma unroll
      for (int kj = 0; kj < 5; ++kj) {
        float v = exact_v(threefry_0_42_pre(base + (uint32_t)cf),
                          lpc[ki * Ww + kj]);
        if (v > best) { best = v; bi = cf; }  // strict >: first-max-wins
        ++cf;
      }
  }
  return bi;
}

// One thread per t-PAIR: samples (b,t,x,y) and (b,t+48,x,y) share the lp
// stream, lpmax, and loop overhead; 2 independent threefry chains = 2x ILP.
// Round-6 lessons baked in:
//  - ki loop MUST be fully unrolled (25-body scheduling window). unroll 1
//    cost 12%: VALUBusy 102 -> 84.
//  - thr_tab ds_read only under the best-update branch (TH is a pure
//    function of BA; between updates the stale TH is the same invariant
//    rounds 2/3 used).
// Phase A: register bits-gate (1 cmp), masked ~12-inst approx top-2 tracker
// (2x v_log2). Phase B: confident approx argmax, or rare exact rescan when
// top-2 gap < MARGIN (covers approx error + exact ties).
__global__ __launch_bounds__(256) void k_sample(const float* __restrict__ logp,
                                                const float* __restrict__ lpmaxa,
                                                int* __restrict__ spikes) {
  __shared__ uint32_t thr_tab[NBIN];
  for (int i = threadIdx.x; i < NBIN; i += 256)
    thr_tab[i] = mkthr(__builtin_fmaf((float)i, 0.03125f, -8.0f));
  __syncthreads();

  int tid = blockIdx.x * 256 + threadIdx.x;  // [0, NSAMP/2)
  int y = tid % OWt;
  int x = (tid / OWt) % OHt;
  int t = (tid / NPIX) % 48;
  int b = tid / (NPIX * 48);
  int sid1 = ((b * TT + t) * OHt + x) * OWt + y;
  // sample 2 = sid1 + 48*NPIX; counter stride = 48*NPIX*600 = 16,588,800
  uint32_t ctr1 = (uint32_t)sid1 * 600u + 42u;  // ks1 pre-added
  const float* lpb = logp + (b * Cc) * (Hh * Ww) + x * Ww + y;
  float lpmax = lpmaxa[(b * OHt + x) * OWt + y];
  // bin index: bidx = fma(bestA, 32, K) = 32*(v - lpmax + 8) + 255 biased
  float K = __builtin_fmaf(-32.0f, lpmax, 255.0f + 32.0f * CGUM);

  float bA1 = -1e30f, bA2 = -1e30f;   // approx running max (vh-space)
  float sA1 = -2e30f, sA2 = -2e30f;   // approx running second-max
  int bi1 = 0, bi2 = 0;
  uint32_t th1 = 0u, th2 = 0u;        // 0 => admit-all (warm-up)

#define AUPD(BITS, BA, SA, BI, TH)                                          \
  if ((BITS) >= (TH)) {                                                     \
    uint32_t key = (BITS) >> 9;                                             \
    float f = __uint_as_float(key | 0x3f800000u) - 1.0f;                    \
    float u = (f == 0.0f) ? 1.17549435e-38f : f;                            \
    float lg = __log2f(u);                       /* < 0 always */           \
    float n = __log2f(-lg);                                                 \
    float vh = __builtin_fmaf(-LN2, n, lp);      /* ~ v - CGUM */           \
    SA = fmaxf(SA, fminf(BA, vh));                                          \
    if (vh > BA) {                                                          \
      BA = vh;                                                              \
      BI = cf;                                                              \
      float bx = __builtin_fmaf(vh, 32.0f, K);                              \
      bx = fminf(fmaxf(bx, 0.0f), 639.0f);                                  \
      TH = thr_tab[(int)bx];                                                \
    }                                                                       \
  }

  int cf = 0;
  #pragma unroll 1
  for (int c = 0; c < Cc; ++c) {
    const float* lpc = lpb + c * (Hh * Ww);
    #pragma unroll
    for (int ki = 0; ki < 5; ++ki) {
      #pragma unroll
      for (int kj = 0; kj < 5; ++kj) {
        float lp = lpc[ki * Ww + kj];
        uint32_t c1 = ctr1 + (uint32_t)cf;
        uint32_t bb1 = threefry_0_42_pre(c1);
        uint32_t bb2 = threefry_0_42_pre(c1 + 16588800u);
        AUPD(bb1, bA1, sA1, bi1, th1)
        AUPD(bb2, bA2, sA2, bi2, th2)
        ++cf;
      }
    }
  }
#undef AUPD

  // Phase B: resolve. Confident if top-2 approx gap >= MARGIN.
  spikes[sid1] = (bA1 - sA1 >= MARGIN) ? bi1 : exact_argmax(ctr1, lpb);
  spikes[sid1 + 48 * NPIX] =
      (bA2 - sA2 >= MARGIN) ? bi2 : exact_argmax(ctr1 + 16588800u, lpb);
}

// One wave per pixel, 2 neurons per lane; 96 sequential normalized updates.
__global__ __launch_bounds__(256) void k_recur(
    const int* __restrict__ spikes, const float* __restrict__ weights,
    const float* __restrict__ eps_xy, const float* __restrict__ eps_t,
    const float* __restrict__ eps0p, const float* __restrict__ h_init,
    float* __restrict__ out) {
  int wid = blockIdx.x * 4 + (threadIdx.x >> 6);  // pixel id in [0, 18432)
  int lane = threadIdx.x & 63;
  int y = wid % OWt;
  int x = (wid / OWt) % OHt;
  int b = wid / NPIX;
  float g0 = h_init[lane];
  float g1 = h_init[lane + 64];
  float e0 = eps0p[0];
  const int* sp = spikes + (b * TT) * NPIX + x * OWt + y;
  const float* ex = eps_xy + (x * OWt + y) * 25;
  for (int t = 0; t < TT; ++t) {
    int s = sp[t * NPIX];  // wave-uniform
    const float* wr = weights + s * HN;
    float wg0 = wr[lane] * g0;
    float wg1 = wr[lane + 64] * g1;
    float sum = wg0 + wg1;
    #pragma unroll
    for (int off = 32; off > 0; off >>= 1) sum += __shfl_xor(sum, off, 64);
    float es = ex[s % 25] * (eps_t[t] * e0);  // eps * (et * eps0)
    float factor = es / sum;
    if (!__builtin_isfinite(factor)) factor = 0.0f;  // nan_to_num
    float d = 1.0f + es;
    g0 = (g0 + wg0 * factor) / d;
    g1 = (g1 + wg1 * factor) / d;
  }
  out[((b * HN + lane) * OHt + x) * OWt + y] = g0;
  out[((b * HN + lane + 64) * OHt + x) * OWt + y] = g1;
}

extern "C" void kernel_launch(void* const* d_in, const int* in_sizes, int n_in,
                              void* d_out, int out_size, void* d_ws, size_t ws_size,
                              hipStream_t stream) {
  const float* input   = (const float*)d_in[0];
  const float* eps_xy  = (const float*)d_in[1];
  const float* eps0    = (const float*)d_in[2];
  const float* eps_t   = (const float*)d_in[3];
  const float* weights = (const float*)d_in[4];
  const float* h_init  = (const float*)d_in[5];
  // d_in[6] = number_of_spikes (=96, hardcoded)

  float* logp = (float*)d_ws;                                // 602,112 f32
  int* spikes = (int*)((char*)d_ws + NLOG * sizeof(float));  // 1,769,472 i32
  // lpmax (18432 f32) staged in d_out; k_recur fully overwrites it later.
  float* lpmax = (float*)d_out;

  k_log<<<(NLOG + 255) / 256, 256, 0, stream>>>(input, logp);
  k_lpmax<<<(Bn * NPIX + 255) / 256, 256, 0, stream>>>(logp, lpmax);
  k_sample<<<(NSAMP / 2) / 256, 256, 0, stream>>>(logp, lpmax, spikes);
  k_recur<<<(Bn * NPIX) / 4, 256, 0, stream>>>(spikes, weights, eps_xy, eps_t,
                                               eps0, h_init, (float*)d_out);
}